// Round 8
// baseline (338.271 us; speedup 1.0000x reference)
//
#include <hip/hip_runtime.h>

// ---------------------------------------------------------------------------
// 2-layer GCN forward, 8-launch pipeline.
// prepW -> front(hist+gemm1 fused) -> scan1 -> scan2 -> place -> degsort
// -> gg2(gather128+gemm2 fused) -> gather40.
// CSR build is atomic-free (LDS histogram partition). GEMMs are bf16 MFMA,
// f32 accum. H1 unscaled bf16 (gg2 applies dinv[src] per edge); H2 pre-scaled.
// ---------------------------------------------------------------------------

typedef unsigned int u32;
typedef unsigned short u16;
typedef __attribute__((ext_vector_type(8))) short short8;
typedef __attribute__((ext_vector_type(4))) float floatx4;

#define CHUNK 4096            // edges per histogram/place block

static __device__ inline u16 f2bf(float f) {
    u32 u = __float_as_uint(f);
    return (u16)((u + 0x7FFFu + ((u >> 16) & 1u)) >> 16);   // RNE
}
static __device__ inline u32 pack2(float a, float b) {
    return (u32)f2bf(a) | ((u32)f2bf(b) << 16);
}
static __device__ inline float bflo(u32 u) { return __uint_as_float(u << 16); }
static __device__ inline float bfhi(u32 u) { return __uint_as_float(u & 0xffff0000u); }

// wave-local int64-vs-int32 storage detection: sample 64 odd int32 slots of
// the first 64 index values; all-zero => int64 (high words), else int32.
static __device__ inline bool detect_is64(const int* e32, int lane) {
    bool nz = e32[2 * lane + 1] != 0;
    return __ballot(nz) == 0ull;
}

// ---- W1 [128,128] -> WTb [c][k] bf16; W2 [128,40] -> W2Tb [48][128] bf16 ---
__global__ void k_prepW(const float* __restrict__ W1, const float* __restrict__ W2,
                        u16* __restrict__ WTb, u16* __restrict__ W2Tb) {
    int id = blockIdx.x * 256 + threadIdx.x;
    if (id < 16384) {
        int k = id >> 7, c = id & 127;           // W1[k][c]
        WTb[c * 128 + k] = f2bf(W1[id]);
    } else {
        int id2 = id - 16384;
        if (id2 < 6144) {                        // 48 x 128, zero-pad cols 40+
            int c = id2 >> 7, k = id2 & 127;
            W2Tb[id2] = f2bf(c < 40 ? W2[k * 40 + c] : 0.f);
        }
    }
}

// ---- fused front: blocks [0,NC) = per-chunk bucket histogram,
//      blocks [NC, NC+G1) = GEMM1 (MFMA, unscaled bf16 out) -----------------
__global__ __launch_bounds__(256) void k_front(const void* __restrict__ e_raw,
                                               int E, int NC, int NB,
                                               int* __restrict__ histG,
                                               const float* __restrict__ X,
                                               const u16* __restrict__ WTb,
                                               u16* __restrict__ H1s, int n) {
    __shared__ u32 smem[64 * 68 + 128 * 68];     // 52,224 B, shared by roles
    const int tid = threadIdx.x;
    if ((int)blockIdx.x < NC) {
        // ---------- histogram role ----------
        int* h = (int*)smem;
        h[tid] = 0; h[tid + 256] = 0;
        __syncthreads();
        const int* e32 = (const int*)e_raw;
        bool is64 = detect_is64(e32, tid & 63);
        int c = blockIdx.x;
        int j0 = c * CHUNK, j1 = min(E, j0 + CHUNK);
        for (int j = j0 + tid; j < j1; j += 256) {
            int d = is64 ? (int)((const long long*)e_raw)[E + j] : e32[E + j];
            atomicAdd(&h[d >> 8], 1);
        }
        __syncthreads();
        for (int b = tid; b < NB; b += 256) histG[(size_t)b * NC + c] = h[b];
        return;
    }
    // ---------- GEMM1 role ----------
    u32* As = smem;                  // [row][k/2], stride 68
    u32* Bs = smem + 64 * 68;        // [col][k/2], stride 68
    const int row0 = ((int)blockIdx.x - NC) * 64;
#pragma unroll
    for (int it = 0; it < 8; it++) {        // stage X, f32 -> bf16
        int i = tid + it * 256;             // 2048 float4
        int r = i >> 5;
        int c4 = (i & 31) << 2;
        int gr = row0 + r;
        float4 v = make_float4(0.f, 0.f, 0.f, 0.f);
        if (gr < n) v = *(const float4*)(X + (size_t)gr * 128 + c4);
        uint2 p;
        p.x = pack2(v.x, v.y);
        p.y = pack2(v.z, v.w);
        *(uint2*)&As[r * 68 + (c4 >> 1)] = p;
    }
#pragma unroll
    for (int it = 0; it < 8; it++) {        // stage WTb (straight copy)
        int i = tid + it * 256;             // 2048 uint4
        int r = i >> 4;
        int c4 = (i & 15) << 2;
        *(uint4*)&Bs[r * 68 + c4] =
            *(const uint4*)((const u32*)WTb + (size_t)r * 64 + c4);
    }
    __syncthreads();

    const int lane = tid & 63;
    const int wave = tid >> 6;
    const int wr = wave >> 1;
    const int wc = wave & 1;
    const int mrow = lane & 15;
    const int quad = lane >> 4;

    floatx4 acc[2][4] = {};
    for (int k0 = 0; k0 < 128; k0 += 32) {
        int koff = (k0 >> 1) + quad * 4;
        short8 a[2], b[4];
#pragma unroll
        for (int i = 0; i < 2; i++)
            a[i] = *(const short8*)&As[((wr * 2 + i) * 16 + mrow) * 68 + koff];
#pragma unroll
        for (int j = 0; j < 4; j++)
            b[j] = *(const short8*)&Bs[((wc * 4 + j) * 16 + mrow) * 68 + koff];
#pragma unroll
        for (int i = 0; i < 2; i++)
#pragma unroll
            for (int j = 0; j < 4; j++)
                acc[i][j] = __builtin_amdgcn_mfma_f32_16x16x32_bf16(
                    a[i], b[j], acc[i][j], 0, 0, 0);
    }
#pragma unroll
    for (int i = 0; i < 2; i++) {
        int gr0 = row0 + (wr * 2 + i) * 16 + quad * 4;
#pragma unroll
        for (int j = 0; j < 4; j++) {
            int gcol = (wc * 4 + j) * 16 + mrow;
#pragma unroll
            for (int rg = 0; rg < 4; rg++) {
                int grow = gr0 + rg;
                if (grow < n)
                    H1s[(size_t)grow * 128 + gcol] = f2bf(acc[i][j][rg]);
            }
        }
    }
}

// ---- exclusive scan over histG (NH entries), partial + block sums ----------
__global__ void k_scan1(const int* __restrict__ in, int* __restrict__ out,
                        int* __restrict__ bsum, int n) {
    __shared__ int sh[256];
    int i = blockIdx.x * 256 + threadIdx.x;
    int v = (i < n) ? in[i] : 0;
    sh[threadIdx.x] = v;
    __syncthreads();
    for (int off = 1; off < 256; off <<= 1) {
        int t = (threadIdx.x >= off) ? sh[threadIdx.x - off] : 0;
        __syncthreads();
        sh[threadIdx.x] += t;
        __syncthreads();
    }
    if (i < n) out[i] = sh[threadIdx.x] - v;             // exclusive partial
    if (threadIdx.x == 255) bsum[blockIdx.x] = sh[255];
}

__global__ void k_scan2(int* __restrict__ bsum, int nb) {   // nb <= 1024
    __shared__ int sh[1024];
    int t = threadIdx.x;
    int v = (t < nb) ? bsum[t] : 0;
    sh[t] = v;
    __syncthreads();
    for (int off = 1; off < 1024; off <<= 1) {
        int u = (t >= off) ? sh[t - off] : 0;
        __syncthreads();
        sh[t] += u;
        __syncthreads();
    }
    if (t < nb) bsum[t] = sh[t] - v;                     // exclusive
}

// ---- place edges into bucket runs (LDS cursors; scan fixup inline) ---------
__global__ __launch_bounds__(256) void k_place(const void* __restrict__ e_raw,
                                               const int* __restrict__ histOff,
                                               const int* __restrict__ bsumH,
                                               u32* __restrict__ tmp,
                                               int E, int NB, int NC) {
    __shared__ int cur[512];
    int c = blockIdx.x;
    int t = threadIdx.x;
    for (int b = t; b < NB; b += 256) {
        int idx = b * NC + c;
        cur[b] = histOff[idx] + bsumH[idx >> 8];
    }
    __syncthreads();
    const int* e32 = (const int*)e_raw;
    bool is64 = detect_is64(e32, t & 63);
    int j0 = c * CHUNK, j1 = min(E, j0 + CHUNK);
    for (int j = j0 + t; j < j1; j += 256) {
        int s, d;
        if (is64) {
            s = (int)((const long long*)e_raw)[j];
            d = (int)((const long long*)e_raw)[E + j];
        } else {
            s = e32[j];
            d = e32[E + j];
        }
        int pos = atomicAdd(&cur[d >> 8], 1);
        tmp[pos] = (u32)s | ((u32)(d & 255) << 24);   // s < 2^24
    }
}

// ---- fused deg+sort: per-bucket degree, dinv, exact rowStart, then place
//      records into exact per-node CSR order (all LDS-cursor) ---------------
__global__ __launch_bounds__(256) void k_degsort(const u32* __restrict__ tmp,
                                                 const int* __restrict__ histOff,
                                                 const int* __restrict__ bsumH,
                                                 int* __restrict__ degI,
                                                 float* __restrict__ dinv,
                                                 int* __restrict__ rs,
                                                 int* __restrict__ eSrc,
                                                 int n, int NB, int NC, int E) {
    __shared__ int cnt[256];
    __shared__ int sh[256];
    __shared__ int cur[256];
    int b = blockIdx.x;
    int t = threadIdx.x;
    cnt[t] = 0;
    __syncthreads();
    int i0 = b * NC;
    int seg0 = histOff[i0] + bsumH[i0 >> 8];
    int seg1 = E;
    if (b + 1 < NB) {
        int i1 = (b + 1) * NC;
        seg1 = histOff[i1] + bsumH[i1 >> 8];
    }
    for (int j = seg0 + t; j < seg1; j += 256) atomicAdd(&cnt[tmp[j] >> 24], 1);
    __syncthreads();
    int v = cnt[t];
    sh[t] = v;
    __syncthreads();
    for (int off = 1; off < 256; off <<= 1) {
        int u = (t >= off) ? sh[t - off] : 0;
        __syncthreads();
        sh[t] += u;
        __syncthreads();
    }
    int myStart = seg0 + sh[t] - v;               // exclusive within bucket
    cur[t] = myStart;
    int node = b * 256 + t;
    if (node < n) {
        degI[node] = v;
        dinv[node] = rsqrtf((float)v + 1.0f);     // +1 self-loop
        rs[node] = myStart;
    }
    __syncthreads();
    for (int j = seg0 + t; j < seg1; j += 256) {
        u32 rec = tmp[j];
        int dl = rec >> 24;
        int s = (int)(rec & 0x00FFFFFFu);
        int pos = atomicAdd(&cur[dl], 1);
        eSrc[pos] = s;
    }
}

// ---- fused layer-2: gather128 (relu+bias+self) -> LDS A-tile -> MFMA gemm2 -
// block = 64 nodes; wave w gathers nodes [row0+16w, row0+16w+16), writing
// packed bf16 rows into As; then standard 64x48 MFMA with W2Tb, *dinv out.
__global__ __launch_bounds__(256) void k_gg2(
    const u32* __restrict__ Hb, const int* __restrict__ rs,
    const int* __restrict__ degI, const int* __restrict__ eSrc,
    const float* __restrict__ dinv, const float* __restrict__ b1,
    const u16* __restrict__ W2Tb, u16* __restrict__ H2s, int n) {
    __shared__ u32 As[64 * 68];      // gather results, gemm A-layout
    __shared__ u32 Bs[48 * 68];      // W2^T
    const int tid = threadIdx.x;
    const int lane = tid & 63;
    const int wave = tid >> 6;
    const int row0 = blockIdx.x * 64;
#pragma unroll
    for (int it = 0; it < 3; it++) {        // stage W2Tb (768 uint4)
        int i = tid + it * 256;
        int r = i >> 4;
        int c4 = (i & 15) << 2;
        *(uint4*)&Bs[r * 68 + c4] =
            *(const uint4*)((const u32*)W2Tb + (size_t)r * 64 + c4);
    }
    // ---- gather phase: 16 nodes per wave --------------------------------
    float2 bv = *(const float2*)(b1 + lane * 2);
    for (int i = 0; i < 16; i++) {
        int node = row0 + wave * 16 + i;
        if (node >= n) break;
        int start = rs[node];
        int deg = degI[node];
        float ax = 0.f, ay = 0.f;
        for (int base = 0; base < deg; base += 64) {
            int mS = 0;
            float mW = 0.f;
            if (base + lane < deg) { mS = eSrc[start + base + lane]; mW = dinv[mS]; }
            int cnt = min(64, deg - base);
            int t = 0;
            for (; t + 8 <= cnt; t += 8) {       // 8-way MLP
                int s0 = __shfl(mS, t + 0), s1 = __shfl(mS, t + 1);
                int s2 = __shfl(mS, t + 2), s3 = __shfl(mS, t + 3);
                int s4 = __shfl(mS, t + 4), s5 = __shfl(mS, t + 5);
                int s6 = __shfl(mS, t + 6), s7 = __shfl(mS, t + 7);
                float w0 = __shfl(mW, t + 0), w1 = __shfl(mW, t + 1);
                float w2 = __shfl(mW, t + 2), w3 = __shfl(mW, t + 3);
                float w4 = __shfl(mW, t + 4), w5 = __shfl(mW, t + 5);
                float w6 = __shfl(mW, t + 6), w7 = __shfl(mW, t + 7);
                u32 u0 = Hb[(size_t)s0 * 64 + lane];
                u32 u1 = Hb[(size_t)s1 * 64 + lane];
                u32 u2 = Hb[(size_t)s2 * 64 + lane];
                u32 u3 = Hb[(size_t)s3 * 64 + lane];
                u32 u4 = Hb[(size_t)s4 * 64 + lane];
                u32 u5 = Hb[(size_t)s5 * 64 + lane];
                u32 u6 = Hb[(size_t)s6 * 64 + lane];
                u32 u7 = Hb[(size_t)s7 * 64 + lane];
                ax = fmaf(w0, bflo(u0), ax); ay = fmaf(w0, bfhi(u0), ay);
                ax = fmaf(w1, bflo(u1), ax); ay = fmaf(w1, bfhi(u1), ay);
                ax = fmaf(w2, bflo(u2), ax); ay = fmaf(w2, bfhi(u2), ay);
                ax = fmaf(w3, bflo(u3), ax); ay = fmaf(w3, bfhi(u3), ay);
                ax = fmaf(w4, bflo(u4), ax); ay = fmaf(w4, bfhi(u4), ay);
                ax = fmaf(w5, bflo(u5), ax); ay = fmaf(w5, bfhi(u5), ay);
                ax = fmaf(w6, bflo(u6), ax); ay = fmaf(w6, bfhi(u6), ay);
                ax = fmaf(w7, bflo(u7), ax); ay = fmaf(w7, bfhi(u7), ay);
            }
            for (; t < cnt; t++) {
                int s = __shfl(mS, t);
                float w = __shfl(mW, t);
                u32 u = Hb[(size_t)s * 64 + lane];
                ax = fmaf(w, bflo(u), ax); ay = fmaf(w, bfhi(u), ay);
            }
        }
        float di = dinv[node];
        u32 us = Hb[(size_t)node * 64 + lane];   // self term (unscaled)
        float inx = fmaf(di, bflo(us), ax);
        float iny = fmaf(di, bfhi(us), ay);
        float rx = fmaxf(fmaf(di, inx, bv.x), 0.f);
        float ry = fmaxf(fmaf(di, iny, bv.y), 0.f);
        As[(wave * 16 + i) * 68 + lane] = pack2(rx, ry);
    }
    __syncthreads();
    // ---- gemm2 phase: 64x48 MFMA, K=128 ---------------------------------
    const int mrow = lane & 15;
    const int quad = lane >> 4;
    floatx4 acc[3] = {};
    for (int k0 = 0; k0 < 128; k0 += 32) {
        int koff = (k0 >> 1) + quad * 4;
        short8 a = *(const short8*)&As[(wave * 16 + mrow) * 68 + koff];
#pragma unroll
        for (int j = 0; j < 3; j++) {
            short8 b = *(const short8*)&Bs[(j * 16 + mrow) * 68 + koff];
            acc[j] = __builtin_amdgcn_mfma_f32_16x16x32_bf16(a, b, acc[j], 0, 0, 0);
        }
    }
    int gr0 = row0 + wave * 16 + quad * 4;
    float dv[4];
#pragma unroll
    for (int rg = 0; rg < 4; rg++)
        dv[rg] = (gr0 + rg < n) ? dinv[gr0 + rg] : 0.f;
#pragma unroll
    for (int j = 0; j < 3; j++) {
        int gcol = j * 16 + mrow;
        if (gcol < 40) {
#pragma unroll
            for (int rg = 0; rg < 4; rg++) {
                int grow = gr0 + rg;
                if (grow < n)
                    H2s[(size_t)grow * 40 + gcol] = f2bf(dv[rg] * acc[j][rg]);
            }
        }
    }
}

// ---- wave-per-node gather, 40 feats (pre-scaled bf16), 3 subgroups ---------
__global__ __launch_bounds__(256) void k_gather40(
    const u32* __restrict__ H2b, const int* __restrict__ rs,
    const int* __restrict__ degI, const int* __restrict__ eSrc,
    const float* __restrict__ dinv, const float* __restrict__ b2,
    float* __restrict__ out, int n) {
    int wave = threadIdx.x >> 6;
    int lane = threadIdx.x & 63;
    int node = blockIdx.x * 4 + wave;
    if (node >= n) return;
    int start = rs[node];
    int deg = degI[node];
    int g = lane / 20;             // subgroup 0..2 active, 3 idle (lanes 60-63)
    int l = lane - g * 20;         // feature-pair index 0..19
    float ax = 0.f, ay = 0.f;
    for (int base = 0; base < deg; base += 64) {
        int mS = 0;
        if (base + lane < deg) mS = eSrc[start + base + lane];
        int cnt = min(64, deg - base);
        for (int t = 0; t < cnt; t += 3) {
            int e = (t + g) & 63;
            int s = __shfl(mS, e);
            if (g < 3 && t + g < cnt) {
                u32 u = H2b[(size_t)s * 20 + l];
                ax += bflo(u);
                ay += bfhi(u);
            }
        }
    }
    float x1 = __shfl(ax, (lane + 20) & 63), y1 = __shfl(ay, (lane + 20) & 63);
    float x2 = __shfl(ax, (lane + 40) & 63), y2 = __shfl(ay, (lane + 40) & 63);
    if (lane < 20) {
        float di = dinv[node];
        u32 u = H2b[(size_t)node * 20 + l];
        float2 bv = *(const float2*)(b2 + l * 2);
        float ox = fmaf(di, ax + x1 + x2 + bflo(u), bv.x);
        float oy = fmaf(di, ay + y1 + y2 + bfhi(u), bv.y);
        *(float2*)(out + (size_t)node * 40 + l * 2) = make_float2(ox, oy);
    }
}

extern "C" void kernel_launch(void* const* d_in, const int* in_sizes, int n_in,
                              void* d_out, int out_size, void* d_ws, size_t ws_size,
                              hipStream_t stream) {
    const float* x  = (const float*)d_in[0];
    const void*  e  = d_in[1];
    const float* W1 = (const float*)d_in[2];
    const float* b1 = (const float*)d_in[3];
    const float* W2 = (const float*)d_in[4];
    const float* b2 = (const float*)d_in[5];
    float* out = (float*)d_out;

    const int n = in_sizes[0] / 128;
    const int E = in_sizes[1] / 2;
    const int NB = (n + 255) / 256;          // node buckets (391)
    const int NC = (E + CHUNK - 1) / CHUNK;  // edge chunks (391)
    const int NH = NB * NC;                  // histogram entries (~153k)
    const int nbH = (NH + 255) / 256;        // scan blocks (<=1024 for scan2)
    const int G1 = (n + 63) / 64;            // gemm1 blocks

    // workspace
    int*   degI    = (int*)d_ws;                     // n
    int*   rs      = degI + n;                       // n
    int*   bsumH   = rs + n;                         // 1024
    float* dinv    = (float*)(bsumH + 1024);         // n
    int*   histG   = (int*)(dinv + n);               // NH
    int*   histOff = histG + NH;                     // NH
    size_t off = (size_t)((char*)(histOff + NH) - (char*)d_ws);
    off = (off + 15) & ~(size_t)15;
    u16*   WTb    = (u16*)((char*)d_ws + off);       // 128*128 bf16 (W1^T)
    u16*   W2Tb   = WTb + 16384;                     // 48*128 bf16 (W2^T pad)
    off = (size_t)((char*)(W2Tb + 6144) - (char*)d_ws);
    off = (off + 15) & ~(size_t)15;
    u32*   tmp    = (u32*)((char*)d_ws + off);       // E bucket records
    int*   eSrc   = (int*)(tmp + (size_t)E);         // E CSR src indices
    u16*   H1s    = (u16*)(eSrc + (size_t)E);        // n*128 bf16 (unscaled)
    u32*   H1b    = (u32*)H1s;                       // same memory, [n,64] u32
    u16*   H2s    = (u16*)(H1s + (size_t)n * 128);   // n*40 bf16 (pre-scaled)
    u32*   H2b    = (u32*)H2s;

    k_prepW<<<88, 256, 0, stream>>>(W1, W2, WTb, W2Tb);
    k_front<<<NC + G1, 256, 0, stream>>>(e, E, NC, NB, histG, x, WTb, H1s, n);

    k_scan1<<<nbH, 256, 0, stream>>>(histG, histOff, bsumH, NH);
    k_scan2<<<1, 1024, 0, stream>>>(bsumH, nbH);
    k_place<<<NC, 256, 0, stream>>>(e, histOff, bsumH, tmp, E, NB, NC);

    k_degsort<<<NB, 256, 0, stream>>>(tmp, histOff, bsumH, degI, dinv, rs,
                                      eSrc, n, NB, NC, E);

    k_gg2<<<(n + 63) / 64, 256, 0, stream>>>(H1b, rs, degI, eSrc, dinv,
                                             b1, W2Tb, H2s, n);
    k_gather40<<<(n + 3) / 4, 256, 0, stream>>>(H2b, rs, degI, eSrc, dinv,
                                                b2, out, n);
}

// Round 9
// 306.937 us; speedup vs baseline: 1.1021x; 1.1021x over previous
//
#include <hip/hip_runtime.h>

// ---------------------------------------------------------------------------
// 2-layer GCN forward, 9-launch pipeline.
// prepW -> front(hist+gemm1 fused) -> scan1 -> scan2 -> place -> degsort
// -> gather128 -> gemm2 -> gather40.
// CSR build is atomic-free (LDS histogram partition). GEMMs are bf16 MFMA,
// f32 accum. H1 unscaled bf16 (gather128 applies dinv[src] per edge); H2
// pre-scaled by dinv in gemm2 epilogue.
// NOTE (r8 lesson): gather must stay un-fused from LDS-heavy GEMM — fusion
// halved occupancy (72->36%) and regressed 319->338 us.
// ---------------------------------------------------------------------------

typedef unsigned int u32;
typedef unsigned short u16;
typedef __attribute__((ext_vector_type(8))) short short8;
typedef __attribute__((ext_vector_type(4))) float floatx4;

#define CHUNK 4096            // edges per histogram/place block

static __device__ inline u16 f2bf(float f) {
    u32 u = __float_as_uint(f);
    return (u16)((u + 0x7FFFu + ((u >> 16) & 1u)) >> 16);   // RNE
}
static __device__ inline u32 pack2(float a, float b) {
    return (u32)f2bf(a) | ((u32)f2bf(b) << 16);
}
static __device__ inline float bflo(u32 u) { return __uint_as_float(u << 16); }
static __device__ inline float bfhi(u32 u) { return __uint_as_float(u & 0xffff0000u); }

// wave-local int64-vs-int32 storage detection: sample 64 odd int32 slots of
// the first 64 index values; all-zero => int64 (high words), else int32.
static __device__ inline bool detect_is64(const int* e32, int lane) {
    bool nz = e32[2 * lane + 1] != 0;
    return __ballot(nz) == 0ull;
}

// ---- W1 [128,128] -> WTb [c][k] bf16; W2 [128,40] -> W2Tb [48][128] bf16 ---
__global__ void k_prepW(const float* __restrict__ W1, const float* __restrict__ W2,
                        u16* __restrict__ WTb, u16* __restrict__ W2Tb) {
    int id = blockIdx.x * 256 + threadIdx.x;
    if (id < 16384) {
        int k = id >> 7, c = id & 127;           // W1[k][c]
        WTb[c * 128 + k] = f2bf(W1[id]);
    } else {
        int id2 = id - 16384;
        if (id2 < 6144) {                        // 48 x 128, zero-pad cols 40+
            int c = id2 >> 7, k = id2 & 127;
            W2Tb[id2] = f2bf(c < 40 ? W2[k * 40 + c] : 0.f);
        }
    }
}

// ---- fused front: blocks [0,NC) = per-chunk bucket histogram,
//      blocks [NC, NC+G1) = GEMM1 (MFMA, unscaled bf16 out) -----------------
__global__ __launch_bounds__(256) void k_front(const void* __restrict__ e_raw,
                                               int E, int NC, int NB,
                                               int* __restrict__ histG,
                                               const float* __restrict__ X,
                                               const u16* __restrict__ WTb,
                                               u16* __restrict__ H1s, int n) {
    __shared__ u32 smem[64 * 68 + 128 * 68];     // 52,224 B, shared by roles
    const int tid = threadIdx.x;
    if ((int)blockIdx.x < NC) {
        // ---------- histogram role ----------
        int* h = (int*)smem;
        h[tid] = 0; h[tid + 256] = 0;
        __syncthreads();
        const int* e32 = (const int*)e_raw;
        bool is64 = detect_is64(e32, tid & 63);
        int c = blockIdx.x;
        int j0 = c * CHUNK, j1 = min(E, j0 + CHUNK);
        for (int j = j0 + tid; j < j1; j += 256) {
            int d = is64 ? (int)((const long long*)e_raw)[E + j] : e32[E + j];
            atomicAdd(&h[d >> 8], 1);
        }
        __syncthreads();
        for (int b = tid; b < NB; b += 256) histG[(size_t)b * NC + c] = h[b];
        return;
    }
    // ---------- GEMM1 role ----------
    u32* As = smem;                  // [row][k/2], stride 68
    u32* Bs = smem + 64 * 68;        // [col][k/2], stride 68
    const int row0 = ((int)blockIdx.x - NC) * 64;
#pragma unroll
    for (int it = 0; it < 8; it++) {        // stage X, f32 -> bf16
        int i = tid + it * 256;             // 2048 float4
        int r = i >> 5;
        int c4 = (i & 31) << 2;
        int gr = row0 + r;
        float4 v = make_float4(0.f, 0.f, 0.f, 0.f);
        if (gr < n) v = *(const float4*)(X + (size_t)gr * 128 + c4);
        uint2 p;
        p.x = pack2(v.x, v.y);
        p.y = pack2(v.z, v.w);
        *(uint2*)&As[r * 68 + (c4 >> 1)] = p;
    }
#pragma unroll
    for (int it = 0; it < 8; it++) {        // stage WTb (straight copy)
        int i = tid + it * 256;             // 2048 uint4
        int r = i >> 4;
        int c4 = (i & 15) << 2;
        *(uint4*)&Bs[r * 68 + c4] =
            *(const uint4*)((const u32*)WTb + (size_t)r * 64 + c4);
    }
    __syncthreads();

    const int lane = tid & 63;
    const int wave = tid >> 6;
    const int wr = wave >> 1;
    const int wc = wave & 1;
    const int mrow = lane & 15;
    const int quad = lane >> 4;

    floatx4 acc[2][4] = {};
    for (int k0 = 0; k0 < 128; k0 += 32) {
        int koff = (k0 >> 1) + quad * 4;
        short8 a[2], b[4];
#pragma unroll
        for (int i = 0; i < 2; i++)
            a[i] = *(const short8*)&As[((wr * 2 + i) * 16 + mrow) * 68 + koff];
#pragma unroll
        for (int j = 0; j < 4; j++)
            b[j] = *(const short8*)&Bs[((wc * 4 + j) * 16 + mrow) * 68 + koff];
#pragma unroll
        for (int i = 0; i < 2; i++)
#pragma unroll
            for (int j = 0; j < 4; j++)
                acc[i][j] = __builtin_amdgcn_mfma_f32_16x16x32_bf16(
                    a[i], b[j], acc[i][j], 0, 0, 0);
    }
#pragma unroll
    for (int i = 0; i < 2; i++) {
        int gr0 = row0 + (wr * 2 + i) * 16 + quad * 4;
#pragma unroll
        for (int j = 0; j < 4; j++) {
            int gcol = (wc * 4 + j) * 16 + mrow;
#pragma unroll
            for (int rg = 0; rg < 4; rg++) {
                int grow = gr0 + rg;
                if (grow < n)
                    H1s[(size_t)grow * 128 + gcol] = f2bf(acc[i][j][rg]);
            }
        }
    }
}

// ---- exclusive scan over histG (NH entries), partial + block sums ----------
__global__ void k_scan1(const int* __restrict__ in, int* __restrict__ out,
                        int* __restrict__ bsum, int n) {
    __shared__ int sh[256];
    int i = blockIdx.x * 256 + threadIdx.x;
    int v = (i < n) ? in[i] : 0;
    sh[threadIdx.x] = v;
    __syncthreads();
    for (int off = 1; off < 256; off <<= 1) {
        int t = (threadIdx.x >= off) ? sh[threadIdx.x - off] : 0;
        __syncthreads();
        sh[threadIdx.x] += t;
        __syncthreads();
    }
    if (i < n) out[i] = sh[threadIdx.x] - v;             // exclusive partial
    if (threadIdx.x == 255) bsum[blockIdx.x] = sh[255];
}

__global__ void k_scan2(int* __restrict__ bsum, int nb) {   // nb <= 1024
    __shared__ int sh[1024];
    int t = threadIdx.x;
    int v = (t < nb) ? bsum[t] : 0;
    sh[t] = v;
    __syncthreads();
    for (int off = 1; off < 1024; off <<= 1) {
        int u = (t >= off) ? sh[t - off] : 0;
        __syncthreads();
        sh[t] += u;
        __syncthreads();
    }
    if (t < nb) bsum[t] = sh[t] - v;                     // exclusive
}

// ---- place edges into bucket runs (LDS cursors; scan fixup inline) ---------
__global__ __launch_bounds__(256) void k_place(const void* __restrict__ e_raw,
                                               const int* __restrict__ histOff,
                                               const int* __restrict__ bsumH,
                                               u32* __restrict__ tmp,
                                               int E, int NB, int NC) {
    __shared__ int cur[512];
    int c = blockIdx.x;
    int t = threadIdx.x;
    for (int b = t; b < NB; b += 256) {
        int idx = b * NC + c;
        cur[b] = histOff[idx] + bsumH[idx >> 8];
    }
    __syncthreads();
    const int* e32 = (const int*)e_raw;
    bool is64 = detect_is64(e32, t & 63);
    int j0 = c * CHUNK, j1 = min(E, j0 + CHUNK);
    for (int j = j0 + t; j < j1; j += 256) {
        int s, d;
        if (is64) {
            s = (int)((const long long*)e_raw)[j];
            d = (int)((const long long*)e_raw)[E + j];
        } else {
            s = e32[j];
            d = e32[E + j];
        }
        int pos = atomicAdd(&cur[d >> 8], 1);
        tmp[pos] = (u32)s | ((u32)(d & 255) << 24);   // s < 2^24
    }
}

// ---- fused deg+sort: per-bucket degree, dinv, exact rowStart, then place
//      records into exact per-node CSR order (all LDS-cursor) ---------------
__global__ __launch_bounds__(256) void k_degsort(const u32* __restrict__ tmp,
                                                 const int* __restrict__ histOff,
                                                 const int* __restrict__ bsumH,
                                                 int* __restrict__ degI,
                                                 float* __restrict__ dinv,
                                                 int* __restrict__ rs,
                                                 int* __restrict__ eSrc,
                                                 int n, int NB, int NC, int E) {
    __shared__ int cnt[256];
    __shared__ int sh[256];
    __shared__ int cur[256];
    int b = blockIdx.x;
    int t = threadIdx.x;
    cnt[t] = 0;
    __syncthreads();
    int i0 = b * NC;
    int seg0 = histOff[i0] + bsumH[i0 >> 8];
    int seg1 = E;
    if (b + 1 < NB) {
        int i1 = (b + 1) * NC;
        seg1 = histOff[i1] + bsumH[i1 >> 8];
    }
    for (int j = seg0 + t; j < seg1; j += 256) atomicAdd(&cnt[tmp[j] >> 24], 1);
    __syncthreads();
    int v = cnt[t];
    sh[t] = v;
    __syncthreads();
    for (int off = 1; off < 256; off <<= 1) {
        int u = (t >= off) ? sh[t - off] : 0;
        __syncthreads();
        sh[t] += u;
        __syncthreads();
    }
    int myStart = seg0 + sh[t] - v;               // exclusive within bucket
    cur[t] = myStart;
    int node = b * 256 + t;
    if (node < n) {
        degI[node] = v;
        dinv[node] = rsqrtf((float)v + 1.0f);     // +1 self-loop
        rs[node] = myStart;
    }
    __syncthreads();
    for (int j = seg0 + t; j < seg1; j += 256) {
        u32 rec = tmp[j];
        int dl = rec >> 24;
        int s = (int)(rec & 0x00FFFFFFu);
        int pos = atomicAdd(&cur[dl], 1);
        eSrc[pos] = s;
    }
}

// ---- wave-per-node gather, 128 feats (unscaled bf16 rows, per-edge dinv) ---
// out = relu(dinv_d*(sum dinv_s*h_s + dinv_d*h_d) + b1), packed bf16x2
__global__ __launch_bounds__(256) void k_gather128(
    const u32* __restrict__ Hb, const int* __restrict__ rs,
    const int* __restrict__ degI, const int* __restrict__ eSrc,
    const float* __restrict__ dinv, const float* __restrict__ b1,
    u32* __restrict__ outb, int n) {
    int wave = threadIdx.x >> 6;
    int lane = threadIdx.x & 63;
    int node = blockIdx.x * 4 + wave;
    if (node >= n) return;
    int start = rs[node];
    int deg = degI[node];
    float ax = 0.f, ay = 0.f;
    for (int base = 0; base < deg; base += 64) {
        int mS = 0;
        float mW = 0.f;
        if (base + lane < deg) { mS = eSrc[start + base + lane]; mW = dinv[mS]; }
        int cnt = min(64, deg - base);
        int t = 0;
        for (; t + 8 <= cnt; t += 8) {       // 8-way MLP
            int s0 = __shfl(mS, t + 0), s1 = __shfl(mS, t + 1);
            int s2 = __shfl(mS, t + 2), s3 = __shfl(mS, t + 3);
            int s4 = __shfl(mS, t + 4), s5 = __shfl(mS, t + 5);
            int s6 = __shfl(mS, t + 6), s7 = __shfl(mS, t + 7);
            float w0 = __shfl(mW, t + 0), w1 = __shfl(mW, t + 1);
            float w2 = __shfl(mW, t + 2), w3 = __shfl(mW, t + 3);
            float w4 = __shfl(mW, t + 4), w5 = __shfl(mW, t + 5);
            float w6 = __shfl(mW, t + 6), w7 = __shfl(mW, t + 7);
            u32 u0 = Hb[(size_t)s0 * 64 + lane];
            u32 u1 = Hb[(size_t)s1 * 64 + lane];
            u32 u2 = Hb[(size_t)s2 * 64 + lane];
            u32 u3 = Hb[(size_t)s3 * 64 + lane];
            u32 u4 = Hb[(size_t)s4 * 64 + lane];
            u32 u5 = Hb[(size_t)s5 * 64 + lane];
            u32 u6 = Hb[(size_t)s6 * 64 + lane];
            u32 u7 = Hb[(size_t)s7 * 64 + lane];
            ax = fmaf(w0, bflo(u0), ax); ay = fmaf(w0, bfhi(u0), ay);
            ax = fmaf(w1, bflo(u1), ax); ay = fmaf(w1, bfhi(u1), ay);
            ax = fmaf(w2, bflo(u2), ax); ay = fmaf(w2, bfhi(u2), ay);
            ax = fmaf(w3, bflo(u3), ax); ay = fmaf(w3, bfhi(u3), ay);
            ax = fmaf(w4, bflo(u4), ax); ay = fmaf(w4, bfhi(u4), ay);
            ax = fmaf(w5, bflo(u5), ax); ay = fmaf(w5, bfhi(u5), ay);
            ax = fmaf(w6, bflo(u6), ax); ay = fmaf(w6, bfhi(u6), ay);
            ax = fmaf(w7, bflo(u7), ax); ay = fmaf(w7, bfhi(u7), ay);
        }
        for (; t < cnt; t++) {
            int s = __shfl(mS, t);
            float w = __shfl(mW, t);
            u32 u = Hb[(size_t)s * 64 + lane];
            ax = fmaf(w, bflo(u), ax); ay = fmaf(w, bfhi(u), ay);
        }
    }
    float di = dinv[node];
    u32 us = Hb[(size_t)node * 64 + lane];   // self term (unscaled)
    float inx = fmaf(di, bflo(us), ax);
    float iny = fmaf(di, bfhi(us), ay);
    float2 bv = *(const float2*)(b1 + lane * 2);
    float rx = fmaxf(fmaf(di, inx, bv.x), 0.f);
    float ry = fmaxf(fmaf(di, iny, bv.y), 0.f);
    outb[(size_t)node * 64 + lane] = pack2(rx, ry);
}

// ---- GEMM2 (MFMA bf16): A1b[n,64]u32 @ W2 -> H2s[n,40] bf16, row*dinv ------
__global__ __launch_bounds__(256) void k_gemm2(const u32* __restrict__ A1b,
                                               const u16* __restrict__ W2Tb,
                                               const float* __restrict__ dinv,
                                               u16* __restrict__ H2s, int n) {
    __shared__ u32 As[64 * 68];
    __shared__ u32 Bs[48 * 68];
    const int tid = threadIdx.x;
    const int row0 = blockIdx.x * 64;
#pragma unroll
    for (int it = 0; it < 4; it++) {        // stage A1 rows (already bf16)
        int i = tid + it * 256;             // 1024 uint4
        int r = i >> 4;
        int c4 = (i & 15) << 2;
        int gr = row0 + r;
        uint4 v = make_uint4(0u, 0u, 0u, 0u);
        if (gr < n) v = *(const uint4*)(A1b + (size_t)gr * 64 + c4);
        *(uint4*)&As[r * 68 + c4] = v;
    }
#pragma unroll
    for (int it = 0; it < 3; it++) {        // stage W2Tb (768 uint4)
        int i = tid + it * 256;
        int r = i >> 4;
        int c4 = (i & 15) << 2;
        *(uint4*)&Bs[r * 68 + c4] =
            *(const uint4*)((const u32*)W2Tb + (size_t)r * 64 + c4);
    }
    __syncthreads();

    const int lane = tid & 63;
    const int wave = tid >> 6;
    const int mrow = lane & 15;
    const int quad = lane >> 4;

    floatx4 acc[3] = {};
    for (int k0 = 0; k0 < 128; k0 += 32) {
        int koff = (k0 >> 1) + quad * 4;
        short8 a = *(const short8*)&As[(wave * 16 + mrow) * 68 + koff];
#pragma unroll
        for (int j = 0; j < 3; j++) {
            short8 b = *(const short8*)&Bs[(j * 16 + mrow) * 68 + koff];
            acc[j] = __builtin_amdgcn_mfma_f32_16x16x32_bf16(a, b, acc[j], 0, 0, 0);
        }
    }
    int gr0 = row0 + wave * 16 + quad * 4;
    float dv[4];
#pragma unroll
    for (int rg = 0; rg < 4; rg++)
        dv[rg] = (gr0 + rg < n) ? dinv[gr0 + rg] : 0.f;
#pragma unroll
    for (int j = 0; j < 3; j++) {
        int gcol = j * 16 + mrow;
        if (gcol < 40) {
#pragma unroll
            for (int rg = 0; rg < 4; rg++) {
                int grow = gr0 + rg;
                if (grow < n)
                    H2s[(size_t)grow * 40 + gcol] = f2bf(dv[rg] * acc[j][rg]);
            }
        }
    }
}

// ---- wave-per-node gather, 40 feats (pre-scaled bf16), 3 subgroups ---------
__global__ __launch_bounds__(256) void k_gather40(
    const u32* __restrict__ H2b, const int* __restrict__ rs,
    const int* __restrict__ degI, const int* __restrict__ eSrc,
    const float* __restrict__ dinv, const float* __restrict__ b2,
    float* __restrict__ out, int n) {
    int wave = threadIdx.x >> 6;
    int lane = threadIdx.x & 63;
    int node = blockIdx.x * 4 + wave;
    if (node >= n) return;
    int start = rs[node];
    int deg = degI[node];
    int g = lane / 20;             // subgroup 0..2 active, 3 idle (lanes 60-63)
    int l = lane - g * 20;         // feature-pair index 0..19
    float ax = 0.f, ay = 0.f;
    for (int base = 0; base < deg; base += 64) {
        int mS = 0;
        if (base + lane < deg) mS = eSrc[start + base + lane];
        int cnt = min(64, deg - base);
        for (int t = 0; t < cnt; t += 3) {
            int e = (t + g) & 63;
            int s = __shfl(mS, e);
            if (g < 3 && t + g < cnt) {
                u32 u = H2b[(size_t)s * 20 + l];
                ax += bflo(u);
                ay += bfhi(u);
            }
        }
    }
    float x1 = __shfl(ax, (lane + 20) & 63), y1 = __shfl(ay, (lane + 20) & 63);
    float x2 = __shfl(ax, (lane + 40) & 63), y2 = __shfl(ay, (lane + 40) & 63);
    if (lane < 20) {
        float di = dinv[node];
        u32 u = H2b[(size_t)node * 20 + l];
        float2 bv = *(const float2*)(b2 + l * 2);
        float ox = fmaf(di, ax + x1 + x2 + bflo(u), bv.x);
        float oy = fmaf(di, ay + y1 + y2 + bfhi(u), bv.y);
        *(float2*)(out + (size_t)node * 40 + l * 2) = make_float2(ox, oy);
    }
}

extern "C" void kernel_launch(void* const* d_in, const int* in_sizes, int n_in,
                              void* d_out, int out_size, void* d_ws, size_t ws_size,
                              hipStream_t stream) {
    const float* x  = (const float*)d_in[0];
    const void*  e  = d_in[1];
    const float* W1 = (const float*)d_in[2];
    const float* b1 = (const float*)d_in[3];
    const float* W2 = (const float*)d_in[4];
    const float* b2 = (const float*)d_in[5];
    float* out = (float*)d_out;

    const int n = in_sizes[0] / 128;
    const int E = in_sizes[1] / 2;
    const int NB = (n + 255) / 256;          // node buckets (391)
    const int NC = (E + CHUNK - 1) / CHUNK;  // edge chunks (391)
    const int NH = NB * NC;                  // histogram entries (~153k)
    const int nbH = (NH + 255) / 256;        // scan blocks (<=1024 for scan2)
    const int G1 = (n + 63) / 64;            // gemm1 blocks

    // workspace
    int*   degI    = (int*)d_ws;                     // n
    int*   rs      = degI + n;                       // n
    int*   bsumH   = rs + n;                         // 1024
    float* dinv    = (float*)(bsumH + 1024);         // n
    int*   histG   = (int*)(dinv + n);               // NH
    int*   histOff = histG + NH;                     // NH
    size_t off = (size_t)((char*)(histOff + NH) - (char*)d_ws);
    off = (off + 15) & ~(size_t)15;
    u16*   WTb    = (u16*)((char*)d_ws + off);       // 128*128 bf16 (W1^T)
    u16*   W2Tb   = WTb + 16384;                     // 48*128 bf16 (W2^T pad)
    off = (size_t)((char*)(W2Tb + 6144) - (char*)d_ws);
    off = (off + 15) & ~(size_t)15;
    u32*   tmp    = (u32*)((char*)d_ws + off);       // E bucket records
    int*   eSrc   = (int*)(tmp + (size_t)E);         // E CSR src indices
    u16*   H1s    = (u16*)(eSrc + (size_t)E);        // n*128 bf16 (unscaled)
    u32*   H1b    = (u32*)H1s;                       // same memory, [n,64] u32
    u32*   A1b    = (u32*)(H1s + (size_t)n * 128);   // n*64 u32 (relu out)
    u16*   H2s    = (u16*)(A1b + (size_t)n * 64);    // n*40 bf16 (pre-scaled)
    u32*   H2b    = (u32*)H2s;

    k_prepW<<<88, 256, 0, stream>>>(W1, W2, WTb, W2Tb);
    k_front<<<NC + G1, 256, 0, stream>>>(e, E, NC, NB, histG, x, WTb, H1s, n);

    k_scan1<<<nbH, 256, 0, stream>>>(histG, histOff, bsumH, NH);
    k_scan2<<<1, 1024, 0, stream>>>(bsumH, nbH);
    k_place<<<NC, 256, 0, stream>>>(e, histOff, bsumH, tmp, E, NB, NC);

    k_degsort<<<NB, 256, 0, stream>>>(tmp, histOff, bsumH, degI, dinv, rs,
                                      eSrc, n, NB, NC, E);

    k_gather128<<<(n + 3) / 4, 256, 0, stream>>>(H1b, rs, degI, eSrc, dinv,
                                                 b1, A1b, n);
    k_gemm2<<<(n + 63) / 64, 256, 0, stream>>>(A1b, W2Tb, dinv, H2s, n);
    k_gather40<<<(n + 3) / 4, 256, 0, stream>>>(H2b, rs, degI, eSrc, dinv,
                                                b2, out, n);
}

// Round 10
// 305.576 us; speedup vs baseline: 1.1070x; 1.0045x over previous
//
#include <hip/hip_runtime.h>

// ---------------------------------------------------------------------------
// 2-layer GCN forward, 9-launch pipeline.
// prepW -> front(hist+gemm1 fused) -> scan1 -> scan2 -> place -> degsort
// -> gather128 -> gemm2 -> gather40.
// CSR build is atomic-free (LDS histogram partition). GEMMs are bf16 MFMA,
// f32 accum. H1 unscaled bf16 (gather128 applies dinv[src] per edge); H2
// pre-scaled by dinv in gemm2 epilogue.
// r8 lesson: gather stays un-fused from LDS-heavy GEMM (occupancy is fuel).
// r10: 16-way MLP in gather128; 4-deep load pipelining in gather40.
// ---------------------------------------------------------------------------

typedef unsigned int u32;
typedef unsigned short u16;
typedef __attribute__((ext_vector_type(8))) short short8;
typedef __attribute__((ext_vector_type(4))) float floatx4;

#define CHUNK 4096            // edges per histogram/place block

static __device__ inline u16 f2bf(float f) {
    u32 u = __float_as_uint(f);
    return (u16)((u + 0x7FFFu + ((u >> 16) & 1u)) >> 16);   // RNE
}
static __device__ inline u32 pack2(float a, float b) {
    return (u32)f2bf(a) | ((u32)f2bf(b) << 16);
}
static __device__ inline float bflo(u32 u) { return __uint_as_float(u << 16); }
static __device__ inline float bfhi(u32 u) { return __uint_as_float(u & 0xffff0000u); }

// wave-local int64-vs-int32 storage detection: sample 64 odd int32 slots of
// the first 64 index values; all-zero => int64 (high words), else int32.
static __device__ inline bool detect_is64(const int* e32, int lane) {
    bool nz = e32[2 * lane + 1] != 0;
    return __ballot(nz) == 0ull;
}

// ---- W1 [128,128] -> WTb [c][k] bf16; W2 [128,40] -> W2Tb [48][128] bf16 ---
__global__ void k_prepW(const float* __restrict__ W1, const float* __restrict__ W2,
                        u16* __restrict__ WTb, u16* __restrict__ W2Tb) {
    int id = blockIdx.x * 256 + threadIdx.x;
    if (id < 16384) {
        int k = id >> 7, c = id & 127;           // W1[k][c]
        WTb[c * 128 + k] = f2bf(W1[id]);
    } else {
        int id2 = id - 16384;
        if (id2 < 6144) {                        // 48 x 128, zero-pad cols 40+
            int c = id2 >> 7, k = id2 & 127;
            W2Tb[id2] = f2bf(c < 40 ? W2[k * 40 + c] : 0.f);
        }
    }
}

// ---- fused front: blocks [0,NC) = per-chunk bucket histogram,
//      blocks [NC, NC+G1) = GEMM1 (MFMA, unscaled bf16 out) -----------------
__global__ __launch_bounds__(256) void k_front(const void* __restrict__ e_raw,
                                               int E, int NC, int NB,
                                               int* __restrict__ histG,
                                               const float* __restrict__ X,
                                               const u16* __restrict__ WTb,
                                               u16* __restrict__ H1s, int n) {
    __shared__ u32 smem[64 * 68 + 128 * 68];     // 52,224 B, shared by roles
    const int tid = threadIdx.x;
    if ((int)blockIdx.x < NC) {
        // ---------- histogram role ----------
        int* h = (int*)smem;
        h[tid] = 0; h[tid + 256] = 0;
        __syncthreads();
        const int* e32 = (const int*)e_raw;
        bool is64 = detect_is64(e32, tid & 63);
        int c = blockIdx.x;
        int j0 = c * CHUNK, j1 = min(E, j0 + CHUNK);
        for (int j = j0 + tid; j < j1; j += 256) {
            int d = is64 ? (int)((const long long*)e_raw)[E + j] : e32[E + j];
            atomicAdd(&h[d >> 8], 1);
        }
        __syncthreads();
        for (int b = tid; b < NB; b += 256) histG[(size_t)b * NC + c] = h[b];
        return;
    }
    // ---------- GEMM1 role ----------
    u32* As = smem;                  // [row][k/2], stride 68
    u32* Bs = smem + 64 * 68;        // [col][k/2], stride 68
    const int row0 = ((int)blockIdx.x - NC) * 64;
#pragma unroll
    for (int it = 0; it < 8; it++) {        // stage X, f32 -> bf16
        int i = tid + it * 256;             // 2048 float4
        int r = i >> 5;
        int c4 = (i & 31) << 2;
        int gr = row0 + r;
        float4 v = make_float4(0.f, 0.f, 0.f, 0.f);
        if (gr < n) v = *(const float4*)(X + (size_t)gr * 128 + c4);
        uint2 p;
        p.x = pack2(v.x, v.y);
        p.y = pack2(v.z, v.w);
        *(uint2*)&As[r * 68 + (c4 >> 1)] = p;
    }
#pragma unroll
    for (int it = 0; it < 8; it++) {        // stage WTb (straight copy)
        int i = tid + it * 256;             // 2048 uint4
        int r = i >> 4;
        int c4 = (i & 15) << 2;
        *(uint4*)&Bs[r * 68 + c4] =
            *(const uint4*)((const u32*)WTb + (size_t)r * 64 + c4);
    }
    __syncthreads();

    const int lane = tid & 63;
    const int wave = tid >> 6;
    const int wr = wave >> 1;
    const int wc = wave & 1;
    const int mrow = lane & 15;
    const int quad = lane >> 4;

    floatx4 acc[2][4] = {};
    for (int k0 = 0; k0 < 128; k0 += 32) {
        int koff = (k0 >> 1) + quad * 4;
        short8 a[2], b[4];
#pragma unroll
        for (int i = 0; i < 2; i++)
            a[i] = *(const short8*)&As[((wr * 2 + i) * 16 + mrow) * 68 + koff];
#pragma unroll
        for (int j = 0; j < 4; j++)
            b[j] = *(const short8*)&Bs[((wc * 4 + j) * 16 + mrow) * 68 + koff];
#pragma unroll
        for (int i = 0; i < 2; i++)
#pragma unroll
            for (int j = 0; j < 4; j++)
                acc[i][j] = __builtin_amdgcn_mfma_f32_16x16x32_bf16(
                    a[i], b[j], acc[i][j], 0, 0, 0);
    }
#pragma unroll
    for (int i = 0; i < 2; i++) {
        int gr0 = row0 + (wr * 2 + i) * 16 + quad * 4;
#pragma unroll
        for (int j = 0; j < 4; j++) {
            int gcol = (wc * 4 + j) * 16 + mrow;
#pragma unroll
            for (int rg = 0; rg < 4; rg++) {
                int grow = gr0 + rg;
                if (grow < n)
                    H1s[(size_t)grow * 128 + gcol] = f2bf(acc[i][j][rg]);
            }
        }
    }
}

// ---- exclusive scan over histG (NH entries), partial + block sums ----------
__global__ void k_scan1(const int* __restrict__ in, int* __restrict__ out,
                        int* __restrict__ bsum, int n) {
    __shared__ int sh[256];
    int i = blockIdx.x * 256 + threadIdx.x;
    int v = (i < n) ? in[i] : 0;
    sh[threadIdx.x] = v;
    __syncthreads();
    for (int off = 1; off < 256; off <<= 1) {
        int t = (threadIdx.x >= off) ? sh[threadIdx.x - off] : 0;
        __syncthreads();
        sh[threadIdx.x] += t;
        __syncthreads();
    }
    if (i < n) out[i] = sh[threadIdx.x] - v;             // exclusive partial
    if (threadIdx.x == 255) bsum[blockIdx.x] = sh[255];
}

__global__ void k_scan2(int* __restrict__ bsum, int nb) {   // nb <= 1024
    __shared__ int sh[1024];
    int t = threadIdx.x;
    int v = (t < nb) ? bsum[t] : 0;
    sh[t] = v;
    __syncthreads();
    for (int off = 1; off < 1024; off <<= 1) {
        int u = (t >= off) ? sh[t - off] : 0;
        __syncthreads();
        sh[t] += u;
        __syncthreads();
    }
    if (t < nb) bsum[t] = sh[t] - v;                     // exclusive
}

// ---- place edges into bucket runs (LDS cursors; scan fixup inline) ---------
__global__ __launch_bounds__(256) void k_place(const void* __restrict__ e_raw,
                                               const int* __restrict__ histOff,
                                               const int* __restrict__ bsumH,
                                               u32* __restrict__ tmp,
                                               int E, int NB, int NC) {
    __shared__ int cur[512];
    int c = blockIdx.x;
    int t = threadIdx.x;
    for (int b = t; b < NB; b += 256) {
        int idx = b * NC + c;
        cur[b] = histOff[idx] + bsumH[idx >> 8];
    }
    __syncthreads();
    const int* e32 = (const int*)e_raw;
    bool is64 = detect_is64(e32, t & 63);
    int j0 = c * CHUNK, j1 = min(E, j0 + CHUNK);
    for (int j = j0 + t; j < j1; j += 256) {
        int s, d;
        if (is64) {
            s = (int)((const long long*)e_raw)[j];
            d = (int)((const long long*)e_raw)[E + j];
        } else {
            s = e32[j];
            d = e32[E + j];
        }
        int pos = atomicAdd(&cur[d >> 8], 1);
        tmp[pos] = (u32)s | ((u32)(d & 255) << 24);   // s < 2^24
    }
}

// ---- fused deg+sort: per-bucket degree, dinv, exact rowStart, then place
//      records into exact per-node CSR order (all LDS-cursor) ---------------
__global__ __launch_bounds__(256) void k_degsort(const u32* __restrict__ tmp,
                                                 const int* __restrict__ histOff,
                                                 const int* __restrict__ bsumH,
                                                 int* __restrict__ degI,
                                                 float* __restrict__ dinv,
                                                 int* __restrict__ rs,
                                                 int* __restrict__ eSrc,
                                                 int n, int NB, int NC, int E) {
    __shared__ int cnt[256];
    __shared__ int sh[256];
    __shared__ int cur[256];
    int b = blockIdx.x;
    int t = threadIdx.x;
    cnt[t] = 0;
    __syncthreads();
    int i0 = b * NC;
    int seg0 = histOff[i0] + bsumH[i0 >> 8];
    int seg1 = E;
    if (b + 1 < NB) {
        int i1 = (b + 1) * NC;
        seg1 = histOff[i1] + bsumH[i1 >> 8];
    }
    for (int j = seg0 + t; j < seg1; j += 256) atomicAdd(&cnt[tmp[j] >> 24], 1);
    __syncthreads();
    int v = cnt[t];
    sh[t] = v;
    __syncthreads();
    for (int off = 1; off < 256; off <<= 1) {
        int u = (t >= off) ? sh[t - off] : 0;
        __syncthreads();
        sh[t] += u;
        __syncthreads();
    }
    int myStart = seg0 + sh[t] - v;               // exclusive within bucket
    cur[t] = myStart;
    int node = b * 256 + t;
    if (node < n) {
        degI[node] = v;
        dinv[node] = rsqrtf((float)v + 1.0f);     // +1 self-loop
        rs[node] = myStart;
    }
    __syncthreads();
    for (int j = seg0 + t; j < seg1; j += 256) {
        u32 rec = tmp[j];
        int dl = rec >> 24;
        int s = (int)(rec & 0x00FFFFFFu);
        int pos = atomicAdd(&cur[dl], 1);
        eSrc[pos] = s;
    }
}

// ---- wave-per-node gather, 128 feats (unscaled bf16 rows, per-edge dinv) ---
// out = relu(dinv_d*(sum dinv_s*h_s + dinv_d*h_d) + b1), packed bf16x2
// 16-way MLP unroll (avg deg ~16 -> one full batch per node typically)
__global__ __launch_bounds__(256) void k_gather128(
    const u32* __restrict__ Hb, const int* __restrict__ rs,
    const int* __restrict__ degI, const int* __restrict__ eSrc,
    const float* __restrict__ dinv, const float* __restrict__ b1,
    u32* __restrict__ outb, int n) {
    int wave = threadIdx.x >> 6;
    int lane = threadIdx.x & 63;
    int node = blockIdx.x * 4 + wave;
    if (node >= n) return;
    int start = rs[node];
    int deg = degI[node];
    float ax = 0.f, ay = 0.f;
    for (int base = 0; base < deg; base += 64) {
        int mS = 0;
        float mW = 0.f;
        if (base + lane < deg) { mS = eSrc[start + base + lane]; mW = dinv[mS]; }
        int cnt = min(64, deg - base);
        int t = 0;
        for (; t + 16 <= cnt; t += 16) {     // 16-way MLP
            int ss[16];
            float ww[16];
            u32 uu[16];
#pragma unroll
            for (int q = 0; q < 16; q++) {
                ss[q] = __shfl(mS, t + q);
                ww[q] = __shfl(mW, t + q);
            }
#pragma unroll
            for (int q = 0; q < 16; q++) uu[q] = Hb[(size_t)ss[q] * 64 + lane];
#pragma unroll
            for (int q = 0; q < 16; q++) {
                ax = fmaf(ww[q], bflo(uu[q]), ax);
                ay = fmaf(ww[q], bfhi(uu[q]), ay);
            }
        }
        for (; t + 4 <= cnt; t += 4) {       // 4-way tail
            int s0 = __shfl(mS, t + 0), s1 = __shfl(mS, t + 1);
            int s2 = __shfl(mS, t + 2), s3 = __shfl(mS, t + 3);
            float w0 = __shfl(mW, t + 0), w1 = __shfl(mW, t + 1);
            float w2 = __shfl(mW, t + 2), w3 = __shfl(mW, t + 3);
            u32 u0 = Hb[(size_t)s0 * 64 + lane];
            u32 u1 = Hb[(size_t)s1 * 64 + lane];
            u32 u2 = Hb[(size_t)s2 * 64 + lane];
            u32 u3 = Hb[(size_t)s3 * 64 + lane];
            ax = fmaf(w0, bflo(u0), ax); ay = fmaf(w0, bfhi(u0), ay);
            ax = fmaf(w1, bflo(u1), ax); ay = fmaf(w1, bfhi(u1), ay);
            ax = fmaf(w2, bflo(u2), ax); ay = fmaf(w2, bfhi(u2), ay);
            ax = fmaf(w3, bflo(u3), ax); ay = fmaf(w3, bfhi(u3), ay);
        }
        for (; t < cnt; t++) {
            int s = __shfl(mS, t);
            float w = __shfl(mW, t);
            u32 u = Hb[(size_t)s * 64 + lane];
            ax = fmaf(w, bflo(u), ax); ay = fmaf(w, bfhi(u), ay);
        }
    }
    float di = dinv[node];
    u32 us = Hb[(size_t)node * 64 + lane];   // self term (unscaled)
    float inx = fmaf(di, bflo(us), ax);
    float iny = fmaf(di, bfhi(us), ay);
    float2 bv = *(const float2*)(b1 + lane * 2);
    float rx = fmaxf(fmaf(di, inx, bv.x), 0.f);
    float ry = fmaxf(fmaf(di, iny, bv.y), 0.f);
    outb[(size_t)node * 64 + lane] = pack2(rx, ry);
}

// ---- GEMM2 (MFMA bf16): A1b[n,64]u32 @ W2 -> H2s[n,40] bf16, row*dinv ------
__global__ __launch_bounds__(256) void k_gemm2(const u32* __restrict__ A1b,
                                               const u16* __restrict__ W2Tb,
                                               const float* __restrict__ dinv,
                                               u16* __restrict__ H2s, int n) {
    __shared__ u32 As[64 * 68];
    __shared__ u32 Bs[48 * 68];
    const int tid = threadIdx.x;
    const int row0 = blockIdx.x * 64;
#pragma unroll
    for (int it = 0; it < 4; it++) {        // stage A1 rows (already bf16)
        int i = tid + it * 256;             // 1024 uint4
        int r = i >> 4;
        int c4 = (i & 15) << 2;
        int gr = row0 + r;
        uint4 v = make_uint4(0u, 0u, 0u, 0u);
        if (gr < n) v = *(const uint4*)(A1b + (size_t)gr * 64 + c4);
        *(uint4*)&As[r * 68 + c4] = v;
    }
#pragma unroll
    for (int it = 0; it < 3; it++) {        // stage W2Tb (768 uint4)
        int i = tid + it * 256;
        int r = i >> 4;
        int c4 = (i & 15) << 2;
        *(uint4*)&Bs[r * 68 + c4] =
            *(const uint4*)((const u32*)W2Tb + (size_t)r * 64 + c4);
    }
    __syncthreads();

    const int lane = tid & 63;
    const int wave = tid >> 6;
    const int mrow = lane & 15;
    const int quad = lane >> 4;

    floatx4 acc[3] = {};
    for (int k0 = 0; k0 < 128; k0 += 32) {
        int koff = (k0 >> 1) + quad * 4;
        short8 a = *(const short8*)&As[(wave * 16 + mrow) * 68 + koff];
#pragma unroll
        for (int j = 0; j < 3; j++) {
            short8 b = *(const short8*)&Bs[(j * 16 + mrow) * 68 + koff];
            acc[j] = __builtin_amdgcn_mfma_f32_16x16x32_bf16(a, b, acc[j], 0, 0, 0);
        }
    }
    int gr0 = row0 + wave * 16 + quad * 4;
    float dv[4];
#pragma unroll
    for (int rg = 0; rg < 4; rg++)
        dv[rg] = (gr0 + rg < n) ? dinv[gr0 + rg] : 0.f;
#pragma unroll
    for (int j = 0; j < 3; j++) {
        int gcol = j * 16 + mrow;
        if (gcol < 40) {
#pragma unroll
            for (int rg = 0; rg < 4; rg++) {
                int grow = gr0 + rg;
                if (grow < n)
                    H2s[(size_t)grow * 40 + gcol] = f2bf(dv[rg] * acc[j][rg]);
            }
        }
    }
}

// ---- wave-per-node gather, 40 feats (pre-scaled bf16), 3 subgroups ---------
// 4 edge-triples pipelined per iteration (4 loads in flight per subgroup)
__global__ __launch_bounds__(256) void k_gather40(
    const u32* __restrict__ H2b, const int* __restrict__ rs,
    const int* __restrict__ degI, const int* __restrict__ eSrc,
    const float* __restrict__ dinv, const float* __restrict__ b2,
    float* __restrict__ out, int n) {
    int wave = threadIdx.x >> 6;
    int lane = threadIdx.x & 63;
    int node = blockIdx.x * 4 + wave;
    if (node >= n) return;
    int start = rs[node];
    int deg = degI[node];
    int g = lane / 20;             // subgroup 0..2 active, 3 idle (lanes 60-63)
    int l = lane - g * 20;         // feature-pair index 0..19
    float ax = 0.f, ay = 0.f;
    for (int base = 0; base < deg; base += 64) {
        int mS = 0;
        if (base + lane < deg) mS = eSrc[start + base + lane];
        int cnt = min(64, deg - base);
        for (int t = 0; t < cnt; t += 12) {
            int i0 = t + g, i1 = t + 3 + g, i2 = t + 6 + g, i3 = t + 9 + g;
            int s0 = __shfl(mS, i0 & 63), s1 = __shfl(mS, i1 & 63);
            int s2 = __shfl(mS, i2 & 63), s3 = __shfl(mS, i3 & 63);
            bool v0 = (g < 3) && (i0 < cnt), v1 = (g < 3) && (i1 < cnt);
            bool v2 = (g < 3) && (i2 < cnt), v3 = (g < 3) && (i3 < cnt);
            u32 u0 = H2b[(size_t)s0 * 20 + l];
            u32 u1 = H2b[(size_t)s1 * 20 + l];
            u32 u2 = H2b[(size_t)s2 * 20 + l];
            u32 u3 = H2b[(size_t)s3 * 20 + l];
            if (v0) { ax += bflo(u0); ay += bfhi(u0); }
            if (v1) { ax += bflo(u1); ay += bfhi(u1); }
            if (v2) { ax += bflo(u2); ay += bfhi(u2); }
            if (v3) { ax += bflo(u3); ay += bfhi(u3); }
        }
    }
    float x1 = __shfl(ax, (lane + 20) & 63), y1 = __shfl(ay, (lane + 20) & 63);
    float x2 = __shfl(ax, (lane + 40) & 63), y2 = __shfl(ay, (lane + 40) & 63);
    if (lane < 20) {
        float di = dinv[node];
        u32 u = H2b[(size_t)node * 20 + l];
        float2 bv = *(const float2*)(b2 + l * 2);
        float ox = fmaf(di, ax + x1 + x2 + bflo(u), bv.x);
        float oy = fmaf(di, ay + y1 + y2 + bfhi(u), bv.y);
        *(float2*)(out + (size_t)node * 40 + l * 2) = make_float2(ox, oy);
    }
}

extern "C" void kernel_launch(void* const* d_in, const int* in_sizes, int n_in,
                              void* d_out, int out_size, void* d_ws, size_t ws_size,
                              hipStream_t stream) {
    const float* x  = (const float*)d_in[0];
    const void*  e  = d_in[1];
    const float* W1 = (const float*)d_in[2];
    const float* b1 = (const float*)d_in[3];
    const float* W2 = (const float*)d_in[4];
    const float* b2 = (const float*)d_in[5];
    float* out = (float*)d_out;

    const int n = in_sizes[0] / 128;
    const int E = in_sizes[1] / 2;
    const int NB = (n + 255) / 256;          // node buckets (391)
    const int NC = (E + CHUNK - 1) / CHUNK;  // edge chunks (391)
    const int NH = NB * NC;                  // histogram entries (~153k)
    const int nbH = (NH + 255) / 256;        // scan blocks (<=1024 for scan2)
    const int G1 = (n + 63) / 64;            // gemm1 blocks

    // workspace
    int*   degI    = (int*)d_ws;                     // n
    int*   rs      = degI + n;                       // n
    int*   bsumH   = rs + n;                         // 1024
    float* dinv    = (float*)(bsumH + 1024);         // n
    int*   histG   = (int*)(dinv + n);               // NH
    int*   histOff = histG + NH;                     // NH
    size_t off = (size_t)((char*)(histOff + NH) - (char*)d_ws);
    off = (off + 15) & ~(size_t)15;
    u16*   WTb    = (u16*)((char*)d_ws + off);       // 128*128 bf16 (W1^T)
    u16*   W2Tb   = WTb + 16384;                     // 48*128 bf16 (W2^T pad)
    off = (size_t)((char*)(W2Tb + 6144) - (char*)d_ws);
    off = (off + 15) & ~(size_t)15;
    u32*   tmp    = (u32*)((char*)d_ws + off);       // E bucket records
    int*   eSrc   = (int*)(tmp + (size_t)E);         // E CSR src indices
    u16*   H1s    = (u16*)(eSrc + (size_t)E);        // n*128 bf16 (unscaled)
    u32*   H1b    = (u32*)H1s;                       // same memory, [n,64] u32
    u32*   A1b    = (u32*)(H1s + (size_t)n * 128);   // n*64 u32 (relu out)
    u16*   H2s    = (u16*)(A1b + (size_t)n * 64);    // n*40 bf16 (pre-scaled)
    u32*   H2b    = (u32*)H2s;

    k_prepW<<<88, 256, 0, stream>>>(W1, W2, WTb, W2Tb);
    k_front<<<NC + G1, 256, 0, stream>>>(e, E, NC, NB, histG, x, WTb, H1s, n);

    k_scan1<<<nbH, 256, 0, stream>>>(histG, histOff, bsumH, NH);
    k_scan2<<<1, 1024, 0, stream>>>(bsumH, nbH);
    k_place<<<NC, 256, 0, stream>>>(e, histOff, bsumH, tmp, E, NB, NC);

    k_degsort<<<NB, 256, 0, stream>>>(tmp, histOff, bsumH, degI, dinv, rs,
                                      eSrc, n, NB, NC, E);

    k_gather128<<<(n + 3) / 4, 256, 0, stream>>>(H1b, rs, degI, eSrc, dinv,
                                                 b1, A1b, n);
    k_gemm2<<<(n + 63) / 64, 256, 0, stream>>>(A1b, W2Tb, dinv, H2s, n);
    k_gather40<<<(n + 3) / 4, 256, 0, stream>>>(H2b, rs, degI, eSrc, dinv,
                                                b2, out, n);
}